// Round 1
// baseline (1517.621 us; speedup 1.0000x reference)
//
#include <hip/hip_runtime.h>
#include <cstdint>
#include <cstddef>

#define N_TOKENS 16384
#define HIDDEN 1024
#define FFN 4096
#define NEXP 8
#define BM 128
#define BK 32
#define MAXR (N_TOKENS*2 + NEXP*BM)   /* 33792 padded assignment rows */
#define MAXTILES (MAXR/BM)            /* 264 */

typedef __bf16 bf16;
typedef __attribute__((ext_vector_type(8))) __bf16 bf16x8;
typedef __attribute__((ext_vector_type(4))) __bf16 bf16x4;
typedef __attribute__((ext_vector_type(4))) float f32x4;

__device__ __forceinline__ void gload16(const void* g, void* l) {
  __builtin_amdgcn_global_load_lds((const __attribute__((address_space(1))) void*)g,
                                   (__attribute__((address_space(3))) void*)l, 16, 0, 0);
}

// ---------------- conversion kernels ----------------

__global__ __launch_bounds__(256) void convx_k(const float* __restrict__ x,
                                               bf16* __restrict__ xb) {
  int i = blockIdx.x * 256 + threadIdx.x;              // over float4s
  float4 v = reinterpret_cast<const float4*>(x)[i];
  bf16x4 o = { (bf16)v.x, (bf16)v.y, (bf16)v.z, (bf16)v.w };
  *reinterpret_cast<bf16x4*>(xb + (size_t)i * 4) = o;
}

// src [z][R][C] f32 -> dst [z][C][R] bf16  (transpose + convert)
__global__ __launch_bounds__(256) void transconv_k(const float* __restrict__ src,
                                                   bf16* __restrict__ dst,
                                                   int R, int C) {
  __shared__ float tile[32][33];
  int bx = blockIdx.x * 32;   // col base (C dim)
  int by = blockIdx.y * 32;   // row base (R dim)
  const float* s = src + (size_t)blockIdx.z * R * C;
  bf16* d = dst + (size_t)blockIdx.z * R * C;
  int tx = threadIdx.x, ty = threadIdx.y;
  #pragma unroll
  for (int i = ty; i < 32; i += 8)
    tile[i][tx] = s[(size_t)(by + i) * C + bx + tx];
  __syncthreads();
  #pragma unroll
  for (int i = ty; i < 32; i += 8)
    d[(size_t)(bx + i) * R + by + tx] = (bf16)tile[tx][i];
}

// ---------------- router ----------------

__global__ __launch_bounds__(256) void router_k(const float* __restrict__ x,
                                                const float* __restrict__ wrt,
                                                int* __restrict__ expIdx,
                                                float* __restrict__ expW,
                                                int* __restrict__ counts) {
  int wave = threadIdx.x >> 6;
  int lane = threadIdx.x & 63;
  int n = blockIdx.x * 4 + wave;
  const float* xr = x + (size_t)n * HIDDEN;
  double acc[NEXP];
  #pragma unroll
  for (int e = 0; e < NEXP; ++e) acc[e] = 0.0;
  #pragma unroll
  for (int j = 0; j < 4; ++j) {
    int vi = j * 64 + lane;
    float4 v = reinterpret_cast<const float4*>(xr)[vi];
    int k0 = vi * 4;
    #pragma unroll
    for (int q = 0; q < 4; ++q) {
      float xv = (&v.x)[q];
      const float4* wp = reinterpret_cast<const float4*>(wrt + (size_t)(k0 + q) * NEXP);
      float4 wa = wp[0], wb = wp[1];
      acc[0] += (double)xv * wa.x;  acc[1] += (double)xv * wa.y;
      acc[2] += (double)xv * wa.z;  acc[3] += (double)xv * wa.w;
      acc[4] += (double)xv * wb.x;  acc[5] += (double)xv * wb.y;
      acc[6] += (double)xv * wb.z;  acc[7] += (double)xv * wb.w;
    }
  }
  #pragma unroll
  for (int e = 0; e < NEXP; ++e) {
    #pragma unroll
    for (int off = 32; off > 0; off >>= 1)
      acc[e] += __shfl_xor(acc[e], off);
  }
  if (lane == 0) {
    int e1 = 0;
    #pragma unroll
    for (int e = 1; e < NEXP; ++e) if (acc[e] > acc[e1]) e1 = e;     // strict >: lowest idx on tie
    int e2 = (e1 == 0) ? 1 : 0;
    #pragma unroll
    for (int e = 0; e < NEXP; ++e)
      if (e != e1 && e != e2 && acc[e] > acc[e2]) e2 = e;
    double d = acc[e2] - acc[e1];                                    // <= 0
    float w1v = (float)(1.0 / (1.0 + exp(d)));                       // p1/(p1+p2)
    expIdx[2 * n]     = e1; expIdx[2 * n + 1] = e2;
    expW[2 * n]       = w1v; expW[2 * n + 1]  = 1.0f - w1v;
    atomicAdd(&counts[e1], 1);
    atomicAdd(&counts[e2], 1);
  }
}

// ---------------- segment offsets + scatter ----------------

__global__ void offsets_k(const int* __restrict__ counts,
                          int* __restrict__ padOff, int* __restrict__ cursor) {
  if (threadIdx.x == 0) {
    int o = 0;
    for (int e = 0; e < NEXP; ++e) {
      padOff[e] = o;
      o += ((counts[e] + BM - 1) / BM) * BM;          // 128-aligned segments
    }
    padOff[NEXP] = o;
  }
  if (threadIdx.x < NEXP) cursor[threadIdx.x] = 0;
}

__global__ __launch_bounds__(256) void scatter_k(const int* __restrict__ expIdx,
                                                 const float* __restrict__ expW,
                                                 const int* __restrict__ padOff,
                                                 int* __restrict__ cursor,
                                                 int* __restrict__ rowTok,
                                                 float* __restrict__ rowW) {
  int n = blockIdx.x * 256 + threadIdx.x;
  #pragma unroll
  for (int k = 0; k < 2; ++k) {
    int e = expIdx[2 * n + k];
    int pos = atomicAdd(&cursor[e], 1);
    int r = padOff[e] + pos;
    rowTok[r] = n;
    rowW[r] = expW[2 * n + k];
  }
}

// ---------------- grouped GEMM 1: h = gelu(x_gather @ w1^T) ----------------

__device__ __forceinline__ float gelu_tanh(float v) {
  float c = 0.7978845608028654f * (v + 0.044715f * v * v * v);
  c = fminf(fmaxf(c, -15.f), 15.f);
  float ex = __expf(2.f * c);
  float t = (ex - 1.f) / (ex + 1.f);
  return 0.5f * v * (1.f + t);
}

__global__ __launch_bounds__(256, 2) void gemm1_k(const bf16* __restrict__ xb,
                                                  const bf16* __restrict__ w1bT,
                                                  bf16* __restrict__ h,
                                                  const int* __restrict__ rowTok,
                                                  const int* __restrict__ padOff,
                                                  int tileStart, int rowStart) {
  __shared__ __attribute__((aligned(16))) bf16 As[BM * BK];
  __shared__ __attribute__((aligned(16))) bf16 Bs[BM * BK];
  const int nCT = FFN / 128;                       // 32 col tiles
  int bt = tileStart + (int)blockIdx.x / nCT;
  int ct = (int)blockIdx.x % nCT;
  int r0 = bt * BM;
  if (r0 >= padOff[NEXP]) return;
  int e = 0;
  while (padOff[e + 1] <= r0) ++e;

  int tid = threadIdx.x;
  int lane = tid & 63, wave = tid >> 6;
  const bf16* Bbase = w1bT + ((size_t)e * FFN + (size_t)ct * 128) * HIDDEN;

  const bf16* aSrc[2]; const bf16* bSrc[2]; int ldsOff[2];
  #pragma unroll
  for (int j = 0; j < 2; ++j) {
    int ci = wave * 128 + j * 64 + lane;           // 16B chunk index
    int r = ci >> 2, s = ci & 3;
    int ks = s ^ (r & 3);                          // XOR slot swizzle (pre-swizzled source)
    int tok = rowTok[r0 + r]; if (tok < 0) tok = 0;
    aSrc[j] = xb + (size_t)tok * HIDDEN + ks * 8;
    bSrc[j] = Bbase + (size_t)r * HIDDEN + ks * 8;
    ldsOff[j] = (wave * 128 + j * 64) * 8;
  }
  int g = lane >> 4, lr = lane & 15;
  int wr = wave >> 1, wc = wave & 1;
  int aOff[4], bOff[4];
  #pragma unroll
  for (int m = 0; m < 4; ++m) { int r = wr * 64 + m * 16 + lr; aOff[m] = r * BK + ((g ^ (r & 3)) << 3); }
  #pragma unroll
  for (int n = 0; n < 4; ++n) { int r = wc * 64 + n * 16 + lr; bOff[n] = r * BK + ((g ^ (r & 3)) << 3); }

  f32x4 zero = {0.f, 0.f, 0.f, 0.f};
  f32x4 acc[4][4];
  #pragma unroll
  for (int m = 0; m < 4; ++m)
    #pragma unroll
    for (int n = 0; n < 4; ++n) acc[m][n] = zero;

  for (int k0 = 0; k0 < HIDDEN; k0 += BK) {
    #pragma unroll
    for (int j = 0; j < 2; ++j) {
      gload16(aSrc[j] + k0, &As[ldsOff[j]]);
      gload16(bSrc[j] + k0, &Bs[ldsOff[j]]);
    }
    __syncthreads();
    bf16x8 af[4], bfr[4];
    #pragma unroll
    for (int m = 0; m < 4; ++m) af[m] = *reinterpret_cast<const bf16x8*>(&As[aOff[m]]);
    #pragma unroll
    for (int n = 0; n < 4; ++n) bfr[n] = *reinterpret_cast<const bf16x8*>(&Bs[bOff[n]]);
    #pragma unroll
    for (int m = 0; m < 4; ++m)
      #pragma unroll
      for (int n = 0; n < 4; ++n)
        acc[m][n] = __builtin_amdgcn_mfma_f32_16x16x32_bf16(af[m], bfr[n], acc[m][n], 0, 0, 0);
    __syncthreads();
  }

  int colBase = ct * 128 + wc * 64 + lr;
  #pragma unroll
  for (int m = 0; m < 4; ++m) {
    #pragma unroll
    for (int i = 0; i < 4; ++i) {
      int t = r0 + wr * 64 + m * 16 + g * 4 + i;
      bf16* hp = h + (size_t)(t - rowStart) * FFN + colBase;
      #pragma unroll
      for (int n = 0; n < 4; ++n)
        hp[n * 16] = (bf16)gelu_tanh(acc[m][n][i]);
    }
  }
}

// ---------------- grouped GEMM 2: out += w * (h @ w2^T) ----------------

__global__ __launch_bounds__(256, 2) void gemm2_k(const bf16* __restrict__ h,
                                                  const bf16* __restrict__ w2bT,
                                                  float* __restrict__ out,
                                                  const int* __restrict__ rowTok,
                                                  const float* __restrict__ rowW,
                                                  const int* __restrict__ padOff,
                                                  int tileStart, int rowStart) {
  __shared__ __attribute__((aligned(16))) bf16 As[BM * BK];
  __shared__ __attribute__((aligned(16))) bf16 Bs[BM * BK];
  const int nCT = HIDDEN / 128;                    // 8 col tiles
  int bt = tileStart + (int)blockIdx.x / nCT;
  int ct = (int)blockIdx.x % nCT;
  int r0 = bt * BM;
  if (r0 >= padOff[NEXP]) return;
  int e = 0;
  while (padOff[e + 1] <= r0) ++e;

  int tid = threadIdx.x;
  int lane = tid & 63, wave = tid >> 6;
  const bf16* Bbase = w2bT + ((size_t)e * HIDDEN + (size_t)ct * 128) * FFN;
  const bf16* Arow = h + (size_t)(r0 - rowStart) * FFN;

  const bf16* aSrc[2]; const bf16* bSrc[2]; int ldsOff[2];
  #pragma unroll
  for (int j = 0; j < 2; ++j) {
    int ci = wave * 128 + j * 64 + lane;
    int r = ci >> 2, s = ci & 3;
    int ks = s ^ (r & 3);
    aSrc[j] = Arow + (size_t)r * FFN + ks * 8;
    bSrc[j] = Bbase + (size_t)r * FFN + ks * 8;
    ldsOff[j] = (wave * 128 + j * 64) * 8;
  }
  int g = lane >> 4, lr = lane & 15;
  int wr = wave >> 1, wc = wave & 1;
  int aOff[4], bOff[4];
  #pragma unroll
  for (int m = 0; m < 4; ++m) { int r = wr * 64 + m * 16 + lr; aOff[m] = r * BK + ((g ^ (r & 3)) << 3); }
  #pragma unroll
  for (int n = 0; n < 4; ++n) { int r = wc * 64 + n * 16 + lr; bOff[n] = r * BK + ((g ^ (r & 3)) << 3); }

  f32x4 zero = {0.f, 0.f, 0.f, 0.f};
  f32x4 acc[4][4];
  #pragma unroll
  for (int m = 0; m < 4; ++m)
    #pragma unroll
    for (int n = 0; n < 4; ++n) acc[m][n] = zero;

  for (int k0 = 0; k0 < FFN; k0 += BK) {
    #pragma unroll
    for (int j = 0; j < 2; ++j) {
      gload16(aSrc[j] + k0, &As[ldsOff[j]]);
      gload16(bSrc[j] + k0, &Bs[ldsOff[j]]);
    }
    __syncthreads();
    bf16x8 af[4], bfr[4];
    #pragma unroll
    for (int m = 0; m < 4; ++m) af[m] = *reinterpret_cast<const bf16x8*>(&As[aOff[m]]);
    #pragma unroll
    for (int n = 0; n < 4; ++n) bfr[n] = *reinterpret_cast<const bf16x8*>(&Bs[bOff[n]]);
    #pragma unroll
    for (int m = 0; m < 4; ++m)
      #pragma unroll
      for (int n = 0; n < 4; ++n)
        acc[m][n] = __builtin_amdgcn_mfma_f32_16x16x32_bf16(af[m], bfr[n], acc[m][n], 0, 0, 0);
    __syncthreads();
  }

  int colBase = ct * 128 + wc * 64 + lr;
  #pragma unroll
  for (int m = 0; m < 4; ++m) {
    #pragma unroll
    for (int i = 0; i < 4; ++i) {
      int t = r0 + wr * 64 + m * 16 + g * 4 + i;
      int tok = rowTok[t];
      if (tok >= 0) {
        float wgt = rowW[t];
        float* op = out + (size_t)tok * HIDDEN + colBase;
        #pragma unroll
        for (int n = 0; n < 4; ++n)
          atomicAdd(op + n * 16, wgt * acc[m][n][i]);
      }
    }
  }
}

// ---------------- host ----------------

extern "C" void kernel_launch(void* const* d_in, const int* in_sizes, int n_in,
                              void* d_out, int out_size, void* d_ws, size_t ws_size,
                              hipStream_t stream) {
  const float* x   = (const float*)d_in[0];
  const float* wrt = (const float*)d_in[1];
  const float* w1  = (const float*)d_in[2];
  const float* w2  = (const float*)d_in[3];
  float* out = (float*)d_out;

  char* p = (char*)d_ws;
  size_t off = 0;
  auto alloc = [&](size_t bytes) -> void* {
    void* r = p + off;
    off = (off + bytes + 255) & ~(size_t)255;
    return r;
  };

  int*   counts = (int*)  alloc(NEXP * 4);
  int*   padOff = (int*)  alloc((NEXP + 1) * 4);
  int*   cursor = (int*)  alloc(NEXP * 4);
  int*   expIdx = (int*)  alloc((size_t)N_TOKENS * 2 * 4);
  float* expW   = (float*)alloc((size_t)N_TOKENS * 2 * 4);
  int*   rowTok = (int*)  alloc((size_t)MAXR * 4);
  float* rowW   = (float*)alloc((size_t)MAXR * 4);
  bf16*  xb     = (bf16*) alloc((size_t)N_TOKENS * HIDDEN * 2);
  bf16*  w1bT   = (bf16*) alloc((size_t)NEXP * FFN * HIDDEN * 2);
  bf16*  w2bT   = (bf16*) alloc((size_t)NEXP * FFN * HIDDEN * 2);
  size_t fixed = off;
  bf16* h = (bf16*)(p + fixed);

  size_t tileB = (size_t)BM * FFN * 2;             // 1 MiB per row tile of h
  size_t avail = (ws_size > fixed) ? (ws_size - fixed) : tileB;
  size_t fitSz = avail / tileB;
  int tilesFit = (int)((fitSz < (size_t)MAXTILES) ? fitSz : (size_t)MAXTILES);
  if (tilesFit < 1) tilesFit = 1;
  int nchunks = (MAXTILES + tilesFit - 1) / tilesFit;
  int tpc = (MAXTILES + nchunks - 1) / nchunks;

  hipMemsetAsync(out, 0, (size_t)N_TOKENS * HIDDEN * 4, stream);
  hipMemsetAsync(counts, 0, NEXP * 4, stream);
  hipMemsetAsync(rowTok, 0xFF, (size_t)MAXR * 4, stream);

  convx_k<<<N_TOKENS * HIDDEN / 4 / 256, 256, 0, stream>>>(x, xb);
  transconv_k<<<dim3(FFN / 32, HIDDEN / 32, NEXP), dim3(32, 8, 1), 0, stream>>>(w1, w1bT, HIDDEN, FFN);
  transconv_k<<<dim3(HIDDEN / 32, FFN / 32, NEXP), dim3(32, 8, 1), 0, stream>>>(w2, w2bT, FFN, HIDDEN);
  router_k<<<N_TOKENS / 4, 256, 0, stream>>>(x, wrt, expIdx, expW, counts);
  offsets_k<<<1, 64, 0, stream>>>(counts, padOff, cursor);
  scatter_k<<<N_TOKENS / 256, 256, 0, stream>>>(expIdx, expW, padOff, cursor, rowTok, rowW);

  for (int c = 0; c < nchunks; ++c) {
    int ts = c * tpc;
    int rs = ts * BM;
    gemm1_k<<<tpc * (FFN / 128), 256, 0, stream>>>(xb, w1bT, h, rowTok, padOff, ts, rs);
    gemm2_k<<<tpc * (HIDDEN / 128), 256, 0, stream>>>(h, w2bT, out, rowTok, rowW, padOff, ts, rs);
  }
}

// Round 2
// 1479.893 us; speedup vs baseline: 1.0255x; 1.0255x over previous
//
#include <hip/hip_runtime.h>
#include <cstdint>
#include <cstddef>

#define N_TOKENS 16384
#define HIDDEN 1024
#define FFN 4096
#define NEXP 8
#define BM 128
#define BK 32
#define MAXR (N_TOKENS*2 + NEXP*BM)   /* 33792 padded assignment rows */
#define MAXTILES (MAXR/BM)            /* 264 */

typedef __bf16 bf16;
typedef __attribute__((ext_vector_type(8))) __bf16 bf16x8;
typedef __attribute__((ext_vector_type(4))) __bf16 bf16x4;
typedef __attribute__((ext_vector_type(4))) float f32x4;

__device__ __forceinline__ void gload16(const void* g, void* l) {
  __builtin_amdgcn_global_load_lds((const __attribute__((address_space(1))) void*)g,
                                   (__attribute__((address_space(3))) void*)l, 16, 0, 0);
}

// bijective XCD swizzle (m204): contiguous wg chunk per XCD
__device__ __forceinline__ int xcd_swz(int orig, int nwg) {
  int q = nwg >> 3, r = nwg & 7;
  int xcd = orig & 7, idx = orig >> 3;
  int base = (xcd < r) ? xcd * (q + 1) : r * (q + 1) + (xcd - r) * q;
  return base + idx;
}

// ---------------- conversion kernels ----------------

__global__ __launch_bounds__(256) void convx_k(const float* __restrict__ x,
                                               bf16* __restrict__ xb) {
  int i = blockIdx.x * 256 + threadIdx.x;              // over float4s
  float4 v = reinterpret_cast<const float4*>(x)[i];
  bf16x4 o = { (bf16)v.x, (bf16)v.y, (bf16)v.z, (bf16)v.w };
  *reinterpret_cast<bf16x4*>(xb + (size_t)i * 4) = o;
}

// src [z][R][C] f32 -> dst [z][C][R] bf16  (transpose + convert), 64x64 tiles
__global__ __launch_bounds__(256) void transconv_k(const float* __restrict__ src,
                                                   bf16* __restrict__ dst,
                                                   int R, int C) {
  __shared__ float tile[64][65];
  int bx = blockIdx.x * 64;   // col base (C dim)
  int by = blockIdx.y * 64;   // row base (R dim)
  const float* s = src + (size_t)blockIdx.z * R * C;
  bf16* d = dst + (size_t)blockIdx.z * R * C;
  int tid = threadIdx.x;
  int tc = (tid & 15) * 4;    // col within tile (float4)
  int tr = tid >> 4;          // 0..15
  #pragma unroll
  for (int p = 0; p < 4; ++p) {
    int r = p * 16 + tr;
    float4 v = *reinterpret_cast<const float4*>(s + (size_t)(by + r) * C + bx + tc);
    tile[r][tc] = v.x; tile[r][tc + 1] = v.y; tile[r][tc + 2] = v.z; tile[r][tc + 3] = v.w;
  }
  __syncthreads();
  int wr = (tid & 15) * 4;    // row within tile (bf16x4)
  int wc = tid >> 4;
  #pragma unroll
  for (int p = 0; p < 4; ++p) {
    int c = p * 16 + wc;
    bf16x4 o = { (bf16)tile[wr][c], (bf16)tile[wr + 1][c],
                 (bf16)tile[wr + 2][c], (bf16)tile[wr + 3][c] };
    *reinterpret_cast<bf16x4*>(d + (size_t)(bx + c) * R + by + wr) = o;
  }
}

// ---------------- router ----------------

__global__ __launch_bounds__(256) void router_k(const float* __restrict__ x,
                                                const float* __restrict__ wrt,
                                                int* __restrict__ expIdx,
                                                float* __restrict__ expW,
                                                int* __restrict__ counts) {
  int wave = threadIdx.x >> 6;
  int lane = threadIdx.x & 63;
  int n = blockIdx.x * 4 + wave;
  const float* xr = x + (size_t)n * HIDDEN;
  double acc[NEXP];
  #pragma unroll
  for (int e = 0; e < NEXP; ++e) acc[e] = 0.0;
  #pragma unroll
  for (int j = 0; j < 4; ++j) {
    int vi = j * 64 + lane;
    float4 v = reinterpret_cast<const float4*>(xr)[vi];
    int k0 = vi * 4;
    #pragma unroll
    for (int q = 0; q < 4; ++q) {
      float xv = (&v.x)[q];
      const float4* wp = reinterpret_cast<const float4*>(wrt + (size_t)(k0 + q) * NEXP);
      float4 wa = wp[0], wb = wp[1];
      acc[0] += (double)xv * wa.x;  acc[1] += (double)xv * wa.y;
      acc[2] += (double)xv * wa.z;  acc[3] += (double)xv * wa.w;
      acc[4] += (double)xv * wb.x;  acc[5] += (double)xv * wb.y;
      acc[6] += (double)xv * wb.z;  acc[7] += (double)xv * wb.w;
    }
  }
  #pragma unroll
  for (int e = 0; e < NEXP; ++e) {
    #pragma unroll
    for (int off = 32; off > 0; off >>= 1)
      acc[e] += __shfl_xor(acc[e], off);
  }
  if (lane == 0) {
    int e1 = 0;
    #pragma unroll
    for (int e = 1; e < NEXP; ++e) if (acc[e] > acc[e1]) e1 = e;     // strict >: lowest idx on tie
    int e2 = (e1 == 0) ? 1 : 0;
    #pragma unroll
    for (int e = 0; e < NEXP; ++e)
      if (e != e1 && e != e2 && acc[e] > acc[e2]) e2 = e;
    double d = acc[e2] - acc[e1];                                    // <= 0
    float w1v = (float)(1.0 / (1.0 + exp(d)));                       // p1/(p1+p2)
    expIdx[2 * n]     = e1; expIdx[2 * n + 1] = e2;
    expW[2 * n]       = w1v; expW[2 * n + 1]  = 1.0f - w1v;
    atomicAdd(&counts[e1], 1);
    atomicAdd(&counts[e2], 1);
  }
}

// ---------------- segment offsets + scatter ----------------

__global__ void offsets_k(const int* __restrict__ counts,
                          int* __restrict__ padOff, int* __restrict__ cursor) {
  if (threadIdx.x == 0) {
    int o = 0;
    for (int e = 0; e < NEXP; ++e) {
      padOff[e] = o;
      o += ((counts[e] + BM - 1) / BM) * BM;          // 128-aligned segments
    }
    padOff[NEXP] = o;
  }
  if (threadIdx.x < NEXP) cursor[threadIdx.x] = 0;
}

__global__ __launch_bounds__(256) void scatter_k(const int* __restrict__ expIdx,
                                                 const float* __restrict__ expW,
                                                 const int* __restrict__ padOff,
                                                 int* __restrict__ cursor,
                                                 int* __restrict__ rowTok,
                                                 float* __restrict__ rowW,
                                                 int* __restrict__ tokRow) {
  int n = blockIdx.x * 256 + threadIdx.x;
  #pragma unroll
  for (int k = 0; k < 2; ++k) {
    int e = expIdx[2 * n + k];
    int pos = atomicAdd(&cursor[e], 1);
    int r = padOff[e] + pos;
    rowTok[r] = n;
    rowW[r] = expW[2 * n + k];
    tokRow[2 * n + k] = r;
  }
}

// ---------------- grouped GEMM 1: h = gelu(x_gather @ w1^T) ----------------

__device__ __forceinline__ float gelu_tanh(float v) {
  float c = 0.7978845608028654f * (v + 0.044715f * v * v * v);
  c = fminf(fmaxf(c, -15.f), 15.f);
  float ex = __expf(2.f * c);
  float t = (ex - 1.f) / (ex + 1.f);
  return 0.5f * v * (1.f + t);
}

__global__ __launch_bounds__(256, 2) void gemm1_k(const bf16* __restrict__ xb,
                                                  const bf16* __restrict__ w1bT,
                                                  bf16* __restrict__ h,
                                                  const int* __restrict__ rowTok,
                                                  const int* __restrict__ padOff,
                                                  int tileStart, int rowStart) {
  __shared__ __attribute__((aligned(16))) bf16 As[BM * BK];
  __shared__ __attribute__((aligned(16))) bf16 Bs[BM * BK];
  const int nCT = FFN / 128;                       // 32 col tiles
  int wg = xcd_swz((int)blockIdx.x, (int)gridDim.x);
  int bt = tileStart + wg / nCT;
  int ct = wg % nCT;
  int r0 = bt * BM;
  if (r0 >= padOff[NEXP]) return;
  int e = 0;
  while (padOff[e + 1] <= r0) ++e;

  int tid = threadIdx.x;
  int lane = tid & 63, wave = tid >> 6;
  const bf16* Bbase = w1bT + ((size_t)e * FFN + (size_t)ct * 128) * HIDDEN;

  const bf16* aSrc[2]; const bf16* bSrc[2]; int ldsOff[2];
  #pragma unroll
  for (int j = 0; j < 2; ++j) {
    int ci = wave * 128 + j * 64 + lane;           // 16B chunk index
    int r = ci >> 2, s = ci & 3;
    int ks = s ^ ((r >> 1) & 3);                   // XOR slot swizzle (pre-swizzled source)
    int tok = rowTok[r0 + r]; if (tok < 0) tok = 0;
    aSrc[j] = xb + (size_t)tok * HIDDEN + ks * 8;
    bSrc[j] = Bbase + (size_t)r * HIDDEN + ks * 8;
    ldsOff[j] = (wave * 128 + j * 64) * 8;
  }
  int g = lane >> 4, lr = lane & 15;
  int wr = wave >> 1, wc = wave & 1;
  int aOff[4], bOff[4];
  #pragma unroll
  for (int m = 0; m < 4; ++m) { int r = wr * 64 + m * 16 + lr; aOff[m] = r * BK + ((g ^ ((r >> 1) & 3)) << 3); }
  #pragma unroll
  for (int n = 0; n < 4; ++n) { int r = wc * 64 + n * 16 + lr; bOff[n] = r * BK + ((g ^ ((r >> 1) & 3)) << 3); }

  f32x4 zero = {0.f, 0.f, 0.f, 0.f};
  f32x4 acc[4][4];
  #pragma unroll
  for (int m = 0; m < 4; ++m)
    #pragma unroll
    for (int n = 0; n < 4; ++n) acc[m][n] = zero;

  for (int k0 = 0; k0 < HIDDEN; k0 += BK) {
    #pragma unroll
    for (int j = 0; j < 2; ++j) {
      gload16(aSrc[j] + k0, &As[ldsOff[j]]);
      gload16(bSrc[j] + k0, &Bs[ldsOff[j]]);
    }
    __syncthreads();
    bf16x8 af[4], bfr[4];
    #pragma unroll
    for (int m = 0; m < 4; ++m) af[m] = *reinterpret_cast<const bf16x8*>(&As[aOff[m]]);
    #pragma unroll
    for (int n = 0; n < 4; ++n) bfr[n] = *reinterpret_cast<const bf16x8*>(&Bs[bOff[n]]);
    #pragma unroll
    for (int m = 0; m < 4; ++m)
      #pragma unroll
      for (int n = 0; n < 4; ++n)
        acc[m][n] = __builtin_amdgcn_mfma_f32_16x16x32_bf16(af[m], bfr[n], acc[m][n], 0, 0, 0);
    __syncthreads();
  }

  int colBase = ct * 128 + wc * 64 + lr;
  #pragma unroll
  for (int m = 0; m < 4; ++m) {
    #pragma unroll
    for (int i = 0; i < 4; ++i) {
      int t = r0 + wr * 64 + m * 16 + g * 4 + i;
      bf16* hp = h + (size_t)(t - rowStart) * FFN + colBase;
      #pragma unroll
      for (int n = 0; n < 4; ++n)
        hp[n * 16] = (bf16)gelu_tanh(acc[m][n][i]);
    }
  }
}

// ---------------- grouped GEMM 2: y = h @ w2^T (per-row, no atomics) ----------------

__global__ __launch_bounds__(256, 2) void gemm2_k(const bf16* __restrict__ h,
                                                  const bf16* __restrict__ w2bT,
                                                  float* __restrict__ y,
                                                  const int* __restrict__ padOff,
                                                  int tileStart, int rowStart) {
  __shared__ __attribute__((aligned(16))) bf16 As[BM * BK];
  __shared__ __attribute__((aligned(16))) bf16 Bs[BM * BK];
  const int nCT = HIDDEN / 128;                    // 8 col tiles
  int wg = xcd_swz((int)blockIdx.x, (int)gridDim.x);
  int bt = tileStart + wg / nCT;
  int ct = wg % nCT;
  int r0 = bt * BM;
  if (r0 >= padOff[NEXP]) return;
  int e = 0;
  while (padOff[e + 1] <= r0) ++e;

  int tid = threadIdx.x;
  int lane = tid & 63, wave = tid >> 6;
  const bf16* Bbase = w2bT + ((size_t)e * HIDDEN + (size_t)ct * 128) * FFN;
  const bf16* Arow = h + (size_t)(r0 - rowStart) * FFN;

  const bf16* aSrc[2]; const bf16* bSrc[2]; int ldsOff[2];
  #pragma unroll
  for (int j = 0; j < 2; ++j) {
    int ci = wave * 128 + j * 64 + lane;
    int r = ci >> 2, s = ci & 3;
    int ks = s ^ ((r >> 1) & 3);
    aSrc[j] = Arow + (size_t)r * FFN + ks * 8;
    bSrc[j] = Bbase + (size_t)r * FFN + ks * 8;
    ldsOff[j] = (wave * 128 + j * 64) * 8;
  }
  int g = lane >> 4, lr = lane & 15;
  int wr = wave >> 1, wc = wave & 1;
  int aOff[4], bOff[4];
  #pragma unroll
  for (int m = 0; m < 4; ++m) { int r = wr * 64 + m * 16 + lr; aOff[m] = r * BK + ((g ^ ((r >> 1) & 3)) << 3); }
  #pragma unroll
  for (int n = 0; n < 4; ++n) { int r = wc * 64 + n * 16 + lr; bOff[n] = r * BK + ((g ^ ((r >> 1) & 3)) << 3); }

  f32x4 zero = {0.f, 0.f, 0.f, 0.f};
  f32x4 acc[4][4];
  #pragma unroll
  for (int m = 0; m < 4; ++m)
    #pragma unroll
    for (int n = 0; n < 4; ++n) acc[m][n] = zero;

  for (int k0 = 0; k0 < FFN; k0 += BK) {
    #pragma unroll
    for (int j = 0; j < 2; ++j) {
      gload16(aSrc[j] + k0, &As[ldsOff[j]]);
      gload16(bSrc[j] + k0, &Bs[ldsOff[j]]);
    }
    __syncthreads();
    bf16x8 af[4], bfr[4];
    #pragma unroll
    for (int m = 0; m < 4; ++m) af[m] = *reinterpret_cast<const bf16x8*>(&As[aOff[m]]);
    #pragma unroll
    for (int n = 0; n < 4; ++n) bfr[n] = *reinterpret_cast<const bf16x8*>(&Bs[bOff[n]]);
    #pragma unroll
    for (int m = 0; m < 4; ++m)
      #pragma unroll
      for (int n = 0; n < 4; ++n)
        acc[m][n] = __builtin_amdgcn_mfma_f32_16x16x32_bf16(af[m], bfr[n], acc[m][n], 0, 0, 0);
    __syncthreads();
  }

  int colBase = ct * 128 + wc * 64 + lr;
  #pragma unroll
  for (int m = 0; m < 4; ++m) {
    #pragma unroll
    for (int i = 0; i < 4; ++i) {
      int t = r0 + wr * 64 + m * 16 + g * 4 + i;
      float* yp = y + (size_t)t * HIDDEN + colBase;
      #pragma unroll
      for (int n = 0; n < 4; ++n)
        yp[n * 16] = acc[m][n][i];
    }
  }
}

// ---------------- combine: out[n] = w0*y[r0] + w1*y[r1] ----------------

__global__ __launch_bounds__(256) void combine_k(const float* __restrict__ y,
                                                 const int* __restrict__ tokRow,
                                                 const float* __restrict__ rowW,
                                                 float* __restrict__ out) {
  int n = blockIdx.x;
  int c = threadIdx.x * 4;
  int r0 = tokRow[2 * n], r1 = tokRow[2 * n + 1];
  float w0 = rowW[r0], w1 = rowW[r1];
  float4 a = *reinterpret_cast<const float4*>(y + (size_t)r0 * HIDDEN + c);
  float4 b = *reinterpret_cast<const float4*>(y + (size_t)r1 * HIDDEN + c);
  float4 o = { w0 * a.x + w1 * b.x, w0 * a.y + w1 * b.y,
               w0 * a.z + w1 * b.z, w0 * a.w + w1 * b.w };
  *reinterpret_cast<float4*>(out + (size_t)n * HIDDEN + c) = o;
}

// ---------------- host ----------------

extern "C" void kernel_launch(void* const* d_in, const int* in_sizes, int n_in,
                              void* d_out, int out_size, void* d_ws, size_t ws_size,
                              hipStream_t stream) {
  const float* x   = (const float*)d_in[0];
  const float* wrt = (const float*)d_in[1];
  const float* w1  = (const float*)d_in[2];
  const float* w2  = (const float*)d_in[3];
  float* out = (float*)d_out;

  char* p = (char*)d_ws;
  size_t off = 0;
  auto alloc = [&](size_t bytes) -> void* {
    void* r = p + off;
    off = (off + bytes + 255) & ~(size_t)255;
    return r;
  };

  int*   counts = (int*)  alloc(NEXP * 4);
  int*   padOff = (int*)  alloc((NEXP + 1) * 4);
  int*   cursor = (int*)  alloc(NEXP * 4);
  int*   expIdx = (int*)  alloc((size_t)N_TOKENS * 2 * 4);
  float* expW   = (float*)alloc((size_t)N_TOKENS * 2 * 4);
  int*   rowTok = (int*)  alloc((size_t)MAXR * 4);
  float* rowW   = (float*)alloc((size_t)MAXR * 4);
  int*   tokRow = (int*)  alloc((size_t)N_TOKENS * 2 * 4);
  bf16*  xb     = (bf16*) alloc((size_t)N_TOKENS * HIDDEN * 2);
  bf16*  w1bT   = (bf16*) alloc((size_t)NEXP * FFN * HIDDEN * 2);
  bf16*  w2bT   = (bf16*) alloc((size_t)NEXP * FFN * HIDDEN * 2);
  float* y      = (float*)alloc((size_t)MAXR * HIDDEN * 4);
  size_t fixed = off;
  bf16* h = (bf16*)(p + fixed);

  size_t tileB = (size_t)BM * FFN * 2;             // 1 MiB per row tile of h
  size_t avail = (ws_size > fixed) ? (ws_size - fixed) : tileB;
  size_t fitSz = avail / tileB;
  int tilesFit = (int)((fitSz < (size_t)MAXTILES) ? fitSz : (size_t)MAXTILES);
  if (tilesFit < 1) tilesFit = 1;
  int nchunks = (MAXTILES + tilesFit - 1) / tilesFit;
  int tpc = (MAXTILES + nchunks - 1) / nchunks;

  hipMemsetAsync(counts, 0, NEXP * 4, stream);
  hipMemsetAsync(rowTok, 0xFF, (size_t)MAXR * 4, stream);

  convx_k<<<N_TOKENS * HIDDEN / 4 / 256, 256, 0, stream>>>(x, xb);
  transconv_k<<<dim3(FFN / 64, HIDDEN / 64, NEXP), dim3(256, 1, 1), 0, stream>>>(w1, w1bT, HIDDEN, FFN);
  transconv_k<<<dim3(HIDDEN / 64, FFN / 64, NEXP), dim3(256, 1, 1), 0, stream>>>(w2, w2bT, FFN, HIDDEN);
  router_k<<<N_TOKENS / 4, 256, 0, stream>>>(x, wrt, expIdx, expW, counts);
  offsets_k<<<1, 64, 0, stream>>>(counts, padOff, cursor);
  scatter_k<<<N_TOKENS / 256, 256, 0, stream>>>(expIdx, expW, padOff, cursor, rowTok, rowW, tokRow);

  for (int c = 0; c < nchunks; ++c) {
    int ts = c * tpc;
    int rs = ts * BM;
    gemm1_k<<<tpc * (FFN / 128), 256, 0, stream>>>(xb, w1bT, h, rowTok, padOff, ts, rs);
    gemm2_k<<<tpc * (HIDDEN / 128), 256, 0, stream>>>(h, w2bT, y, padOff, ts, rs);
  }
  combine_k<<<N_TOKENS, 256, 0, stream>>>(y, tokRow, rowW, out);
}

// Round 3
// 1014.979 us; speedup vs baseline: 1.4952x; 1.4581x over previous
//
#include <hip/hip_runtime.h>
#include <cstdint>
#include <cstddef>

#define N_TOKENS 16384
#define HIDDEN 1024
#define FFN 4096
#define NEXP 8
#define BM 128
#define BK 32
#define MAXR (N_TOKENS*2 + NEXP*BM)   /* 33792 padded assignment rows */
#define MAXTILES (MAXR/BM)            /* 264 */

typedef __bf16 bf16;
typedef __attribute__((ext_vector_type(8))) __bf16 bf16x8;
typedef __attribute__((ext_vector_type(4))) __bf16 bf16x4;
typedef __attribute__((ext_vector_type(4))) float f32x4;

__device__ __forceinline__ void gload16(const void* g, void* l) {
  __builtin_amdgcn_global_load_lds((const __attribute__((address_space(1))) void*)g,
                                   (__attribute__((address_space(3))) void*)l, 16, 0, 0);
}

// bijective XCD swizzle (m204): contiguous wg chunk per XCD
__device__ __forceinline__ int xcd_swz(int orig, int nwg) {
  int q = nwg >> 3, r = nwg & 7;
  int xcd = orig & 7, idx = orig >> 3;
  int base = (xcd < r) ? xcd * (q + 1) : r * (q + 1) + (xcd - r) * q;
  return base + idx;
}

// ---------------- conversion kernels ----------------

__global__ __launch_bounds__(256) void convx_k(const float* __restrict__ x,
                                               bf16* __restrict__ xb) {
  int i = blockIdx.x * 256 + threadIdx.x;              // over float4s
  float4 v = reinterpret_cast<const float4*>(x)[i];
  bf16x4 o = { (bf16)v.x, (bf16)v.y, (bf16)v.z, (bf16)v.w };
  *reinterpret_cast<bf16x4*>(xb + (size_t)i * 4) = o;
}

// src [z][R][C] f32 -> dst [z][C][R] bf16  (transpose + convert), 64x64 tiles
__global__ __launch_bounds__(256) void transconv_k(const float* __restrict__ src,
                                                   bf16* __restrict__ dst,
                                                   int R, int C) {
  __shared__ float tile[64][65];
  int bx = blockIdx.x * 64;   // col base (C dim)
  int by = blockIdx.y * 64;   // row base (R dim)
  const float* s = src + (size_t)blockIdx.z * R * C;
  bf16* d = dst + (size_t)blockIdx.z * R * C;
  int tid = threadIdx.x;
  int tc = (tid & 15) * 4;    // col within tile (float4)
  int tr = tid >> 4;          // 0..15
  #pragma unroll
  for (int p = 0; p < 4; ++p) {
    int r = p * 16 + tr;
    float4 v = *reinterpret_cast<const float4*>(s + (size_t)(by + r) * C + bx + tc);
    tile[r][tc] = v.x; tile[r][tc + 1] = v.y; tile[r][tc + 2] = v.z; tile[r][tc + 3] = v.w;
  }
  __syncthreads();
  int wr = (tid & 15) * 4;    // row within tile (bf16x4)
  int wc = tid >> 4;
  #pragma unroll
  for (int p = 0; p < 4; ++p) {
    int c = p * 16 + wc;
    bf16x4 o = { (bf16)tile[wr][c], (bf16)tile[wr + 1][c],
                 (bf16)tile[wr + 2][c], (bf16)tile[wr + 3][c] };
    *reinterpret_cast<bf16x4*>(d + (size_t)(bx + c) * R + by + wr) = o;
  }
}

// ---------------- router: logits (f64, one thread per token,expert) ----------------

__global__ __launch_bounds__(256) void logits_k(const float* __restrict__ x,
                                                const float* __restrict__ wrt,
                                                double* __restrict__ logitsE) {
  __shared__ float wT[NEXP][HIDDEN + 1];    // padded: bank = (e + k) % 32
  int tid = threadIdx.x;
  for (int i = tid; i < HIDDEN * NEXP; i += 256) {
    int k = i >> 3, e = i & 7;
    wT[e][k] = wrt[i];
  }
  __syncthreads();
  int t = blockIdx.x * 32 + (tid >> 3);     // token
  int e = tid & 7;                          // expert
  int goff = ((tid >> 3) & 7) * 4;          // per-group k stagger (bank spread)
  const float* xr = x + (size_t)t * HIDDEN;
  double acc = 0.0;
  #pragma unroll 4
  for (int k = 0; k < HIDDEN; k += 4) {
    int kk = (k + goff) & (HIDDEN - 1);
    float4 v = *reinterpret_cast<const float4*>(xr + kk);   // broadcast across 8 lanes
    acc += (double)v.x * (double)wT[e][kk];
    acc += (double)v.y * (double)wT[e][kk + 1];
    acc += (double)v.z * (double)wT[e][kk + 2];
    acc += (double)v.w * (double)wT[e][kk + 3];
  }
  logitsE[(size_t)e * N_TOKENS + t] = acc;
}

// ---------------- router: top-2 + weights + histogram ----------------

__global__ __launch_bounds__(256) void route_k(const double* __restrict__ logitsE,
                                               int* __restrict__ expIdx,
                                               float* __restrict__ expW,
                                               int* __restrict__ counts) {
  __shared__ int lcnt[NEXP];
  int tid = threadIdx.x;
  if (tid < NEXP) lcnt[tid] = 0;
  __syncthreads();
  int n = blockIdx.x * 256 + tid;
  double lg[NEXP];
  #pragma unroll
  for (int e = 0; e < NEXP; ++e) lg[e] = logitsE[(size_t)e * N_TOKENS + n];  // coalesced
  int e1 = 0;
  #pragma unroll
  for (int e = 1; e < NEXP; ++e) if (lg[e] > lg[e1]) e1 = e;       // strict >: lowest idx wins ties
  int e2 = (e1 == 0) ? 1 : 0;
  #pragma unroll
  for (int e = 0; e < NEXP; ++e)
    if (e != e1 && e != e2 && lg[e] > lg[e2]) e2 = e;
  double d = lg[e2] - lg[e1];                                      // <= 0
  float w1v = (float)(1.0 / (1.0 + exp(d)));                       // p1/(p1+p2)
  expIdx[2 * n]     = e1; expIdx[2 * n + 1] = e2;
  expW[2 * n]       = w1v; expW[2 * n + 1]  = 1.0f - w1v;
  atomicAdd(&lcnt[e1], 1);
  atomicAdd(&lcnt[e2], 1);
  __syncthreads();
  if (tid < NEXP) atomicAdd(&counts[tid], lcnt[tid]);
}

// ---------------- segment offsets + scatter ----------------

__global__ void offsets_k(const int* __restrict__ counts,
                          int* __restrict__ padOff, int* __restrict__ cursor) {
  if (threadIdx.x == 0) {
    int o = 0;
    for (int e = 0; e < NEXP; ++e) {
      padOff[e] = o;
      o += ((counts[e] + BM - 1) / BM) * BM;          // 128-aligned segments
    }
    padOff[NEXP] = o;
  }
  if (threadIdx.x < NEXP) cursor[threadIdx.x] = 0;
}

__global__ __launch_bounds__(256) void scatter_k(const int* __restrict__ expIdx,
                                                 const float* __restrict__ expW,
                                                 const int* __restrict__ padOff,
                                                 int* __restrict__ cursor,
                                                 int* __restrict__ rowTok,
                                                 float* __restrict__ rowW,
                                                 int* __restrict__ tokRow) {
  __shared__ int lcnt[NEXP], lbase[NEXP];
  int tid = threadIdx.x;
  if (tid < NEXP) lcnt[tid] = 0;
  __syncthreads();
  int n = blockIdx.x * 256 + tid;
  int e0 = expIdx[2 * n], e1 = expIdx[2 * n + 1];
  float w0 = expW[2 * n], w1 = expW[2 * n + 1];
  int p0 = atomicAdd(&lcnt[e0], 1);
  int p1 = atomicAdd(&lcnt[e1], 1);
  __syncthreads();
  if (tid < NEXP) lbase[tid] = atomicAdd(&cursor[tid], lcnt[tid]); // 8 global atomics/block
  __syncthreads();
  int r0 = padOff[e0] + lbase[e0] + p0;
  int r1 = padOff[e1] + lbase[e1] + p1;
  rowTok[r0] = n;  rowW[r0] = w0;  tokRow[2 * n]     = r0;
  rowTok[r1] = n;  rowW[r1] = w1;  tokRow[2 * n + 1] = r1;
}

// ---------------- grouped GEMM 1: h = gelu(x_gather @ w1^T) ----------------

__device__ __forceinline__ float gelu_tanh(float v) {
  float c = 0.7978845608028654f * (v + 0.044715f * v * v * v);
  c = fminf(fmaxf(c, -15.f), 15.f);
  float ex = __expf(2.f * c);
  float t = (ex - 1.f) / (ex + 1.f);
  return 0.5f * v * (1.f + t);
}

__global__ __launch_bounds__(256, 2) void gemm1_k(const bf16* __restrict__ xb,
                                                  const bf16* __restrict__ w1bT,
                                                  bf16* __restrict__ h,
                                                  const int* __restrict__ rowTok,
                                                  const int* __restrict__ padOff,
                                                  int tileStart, int rowStart) {
  __shared__ __attribute__((aligned(16))) bf16 As[BM * BK];
  __shared__ __attribute__((aligned(16))) bf16 Bs[BM * BK];
  const int nCT = FFN / 128;                       // 32 col tiles
  int wg = xcd_swz((int)blockIdx.x, (int)gridDim.x);
  int bt = tileStart + wg / nCT;
  int ct = wg % nCT;
  int r0 = bt * BM;
  if (r0 >= padOff[NEXP]) return;
  int e = 0;
  while (padOff[e + 1] <= r0) ++e;

  int tid = threadIdx.x;
  int lane = tid & 63, wave = tid >> 6;
  const bf16* Bbase = w1bT + ((size_t)e * FFN + (size_t)ct * 128) * HIDDEN;

  const bf16* aSrc[2]; const bf16* bSrc[2]; int ldsOff[2];
  #pragma unroll
  for (int j = 0; j < 2; ++j) {
    int ci = wave * 128 + j * 64 + lane;           // 16B chunk index
    int r = ci >> 2, s = ci & 3;
    int ks = s ^ ((r >> 1) & 3);                   // XOR slot swizzle (pre-swizzled source)
    int tok = rowTok[r0 + r]; if (tok < 0) tok = 0;
    aSrc[j] = xb + (size_t)tok * HIDDEN + ks * 8;
    bSrc[j] = Bbase + (size_t)r * HIDDEN + ks * 8;
    ldsOff[j] = (wave * 128 + j * 64) * 8;
  }
  int g = lane >> 4, lr = lane & 15;
  int wr = wave >> 1, wc = wave & 1;
  int aOff[4], bOff[4];
  #pragma unroll
  for (int m = 0; m < 4; ++m) { int r = wr * 64 + m * 16 + lr; aOff[m] = r * BK + ((g ^ ((r >> 1) & 3)) << 3); }
  #pragma unroll
  for (int n = 0; n < 4; ++n) { int r = wc * 64 + n * 16 + lr; bOff[n] = r * BK + ((g ^ ((r >> 1) & 3)) << 3); }

  f32x4 zero = {0.f, 0.f, 0.f, 0.f};
  f32x4 acc[4][4];
  #pragma unroll
  for (int m = 0; m < 4; ++m)
    #pragma unroll
    for (int n = 0; n < 4; ++n) acc[m][n] = zero;

  for (int k0 = 0; k0 < HIDDEN; k0 += BK) {
    #pragma unroll
    for (int j = 0; j < 2; ++j) {
      gload16(aSrc[j] + k0, &As[ldsOff[j]]);
      gload16(bSrc[j] + k0, &Bs[ldsOff[j]]);
    }
    __syncthreads();
    bf16x8 af[4], bfr[4];
    #pragma unroll
    for (int m = 0; m < 4; ++m) af[m] = *reinterpret_cast<const bf16x8*>(&As[aOff[m]]);
    #pragma unroll
    for (int n = 0; n < 4; ++n) bfr[n] = *reinterpret_cast<const bf16x8*>(&Bs[bOff[n]]);
    #pragma unroll
    for (int m = 0; m < 4; ++m)
      #pragma unroll
      for (int n = 0; n < 4; ++n)
        acc[m][n] = __builtin_amdgcn_mfma_f32_16x16x32_bf16(af[m], bfr[n], acc[m][n], 0, 0, 0);
    __syncthreads();
  }

  int colBase = ct * 128 + wc * 64 + lr;
  #pragma unroll
  for (int m = 0; m < 4; ++m) {
    #pragma unroll
    for (int i = 0; i < 4; ++i) {
      int t = r0 + wr * 64 + m * 16 + g * 4 + i;
      bf16* hp = h + (size_t)(t - rowStart) * FFN + colBase;
      #pragma unroll
      for (int n = 0; n < 4; ++n)
        hp[n * 16] = (bf16)gelu_tanh(acc[m][n][i]);
    }
  }
}

// ---------------- grouped GEMM 2: y = h @ w2^T (per-row, no atomics) ----------------

__global__ __launch_bounds__(256, 2) void gemm2_k(const bf16* __restrict__ h,
                                                  const bf16* __restrict__ w2bT,
                                                  float* __restrict__ y,
                                                  const int* __restrict__ padOff,
                                                  int tileStart, int rowStart) {
  __shared__ __attribute__((aligned(16))) bf16 As[BM * BK];
  __shared__ __attribute__((aligned(16))) bf16 Bs[BM * BK];
  const int nCT = HIDDEN / 128;                    // 8 col tiles
  int wg = xcd_swz((int)blockIdx.x, (int)gridDim.x);
  int bt = tileStart + wg / nCT;
  int ct = wg % nCT;
  int r0 = bt * BM;
  if (r0 >= padOff[NEXP]) return;
  int e = 0;
  while (padOff[e + 1] <= r0) ++e;

  int tid = threadIdx.x;
  int lane = tid & 63, wave = tid >> 6;
  const bf16* Bbase = w2bT + ((size_t)e * HIDDEN + (size_t)ct * 128) * FFN;
  const bf16* Arow = h + (size_t)(r0 - rowStart) * FFN;

  const bf16* aSrc[2]; const bf16* bSrc[2]; int ldsOff[2];
  #pragma unroll
  for (int j = 0; j < 2; ++j) {
    int ci = wave * 128 + j * 64 + lane;
    int r = ci >> 2, s = ci & 3;
    int ks = s ^ ((r >> 1) & 3);
    aSrc[j] = Arow + (size_t)r * FFN + ks * 8;
    bSrc[j] = Bbase + (size_t)r * FFN + ks * 8;
    ldsOff[j] = (wave * 128 + j * 64) * 8;
  }
  int g = lane >> 4, lr = lane & 15;
  int wr = wave >> 1, wc = wave & 1;
  int aOff[4], bOff[4];
  #pragma unroll
  for (int m = 0; m < 4; ++m) { int r = wr * 64 + m * 16 + lr; aOff[m] = r * BK + ((g ^ ((r >> 1) & 3)) << 3); }
  #pragma unroll
  for (int n = 0; n < 4; ++n) { int r = wc * 64 + n * 16 + lr; bOff[n] = r * BK + ((g ^ ((r >> 1) & 3)) << 3); }

  f32x4 zero = {0.f, 0.f, 0.f, 0.f};
  f32x4 acc[4][4];
  #pragma unroll
  for (int m = 0; m < 4; ++m)
    #pragma unroll
    for (int n = 0; n < 4; ++n) acc[m][n] = zero;

  for (int k0 = 0; k0 < FFN; k0 += BK) {
    #pragma unroll
    for (int j = 0; j < 2; ++j) {
      gload16(aSrc[j] + k0, &As[ldsOff[j]]);
      gload16(bSrc[j] + k0, &Bs[ldsOff[j]]);
    }
    __syncthreads();
    bf16x8 af[4], bfr[4];
    #pragma unroll
    for (int m = 0; m < 4; ++m) af[m] = *reinterpret_cast<const bf16x8*>(&As[aOff[m]]);
    #pragma unroll
    for (int n = 0; n < 4; ++n) bfr[n] = *reinterpret_cast<const bf16x8*>(&Bs[bOff[n]]);
    #pragma unroll
    for (int m = 0; m < 4; ++m)
      #pragma unroll
      for (int n = 0; n < 4; ++n)
        acc[m][n] = __builtin_amdgcn_mfma_f32_16x16x32_bf16(af[m], bfr[n], acc[m][n], 0, 0, 0);
    __syncthreads();
  }

  int colBase = ct * 128 + wc * 64 + lr;
  #pragma unroll
  for (int m = 0; m < 4; ++m) {
    #pragma unroll
    for (int i = 0; i < 4; ++i) {
      int t = r0 + wr * 64 + m * 16 + g * 4 + i;
      float* yp = y + (size_t)t * HIDDEN + colBase;
      #pragma unroll
      for (int n = 0; n < 4; ++n)
        yp[n * 16] = acc[m][n][i];
    }
  }
}

// ---------------- combine: out[n] = w0*y[r0] + w1*y[r1] ----------------

__global__ __launch_bounds__(256) void combine_k(const float* __restrict__ y,
                                                 const int* __restrict__ tokRow,
                                                 const float* __restrict__ rowW,
                                                 float* __restrict__ out) {
  int n = blockIdx.x;
  int c = threadIdx.x * 4;
  int r0 = tokRow[2 * n], r1 = tokRow[2 * n + 1];
  float w0 = rowW[r0], w1 = rowW[r1];
  float4 a = *reinterpret_cast<const float4*>(y + (size_t)r0 * HIDDEN + c);
  float4 b = *reinterpret_cast<const float4*>(y + (size_t)r1 * HIDDEN + c);
  float4 o = { w0 * a.x + w1 * b.x, w0 * a.y + w1 * b.y,
               w0 * a.z + w1 * b.z, w0 * a.w + w1 * b.w };
  *reinterpret_cast<float4*>(out + (size_t)n * HIDDEN + c) = o;
}

// ---------------- host ----------------

extern "C" void kernel_launch(void* const* d_in, const int* in_sizes, int n_in,
                              void* d_out, int out_size, void* d_ws, size_t ws_size,
                              hipStream_t stream) {
  const float* x   = (const float*)d_in[0];
  const float* wrt = (const float*)d_in[1];
  const float* w1  = (const float*)d_in[2];
  const float* w2  = (const float*)d_in[3];
  float* out = (float*)d_out;

  char* p = (char*)d_ws;
  size_t off = 0;
  auto alloc = [&](size_t bytes) -> void* {
    void* r = p + off;
    off = (off + bytes + 255) & ~(size_t)255;
    return r;
  };

  int*    counts  = (int*)   alloc(NEXP * 4);
  int*    padOff  = (int*)   alloc((NEXP + 1) * 4);
  int*    cursor  = (int*)   alloc(NEXP * 4);
  int*    expIdx  = (int*)   alloc((size_t)N_TOKENS * 2 * 4);
  float*  expW    = (float*) alloc((size_t)N_TOKENS * 2 * 4);
  int*    rowTok  = (int*)   alloc((size_t)MAXR * 4);
  float*  rowW    = (float*) alloc((size_t)MAXR * 4);
  int*    tokRow  = (int*)   alloc((size_t)N_TOKENS * 2 * 4);
  double* logitsE = (double*)alloc((size_t)NEXP * N_TOKENS * 8);
  bf16*   xb      = (bf16*)  alloc((size_t)N_TOKENS * HIDDEN * 2);
  bf16*   w1bT    = (bf16*)  alloc((size_t)NEXP * FFN * HIDDEN * 2);
  bf16*   w2bT    = (bf16*)  alloc((size_t)NEXP * FFN * HIDDEN * 2);
  float*  y       = (float*) alloc((size_t)MAXR * HIDDEN * 4);
  size_t fixed = off;
  bf16* h = (bf16*)(p + fixed);

  size_t tileB = (size_t)BM * FFN * 2;             // 1 MiB per row tile of h
  size_t avail = (ws_size > fixed) ? (ws_size - fixed) : tileB;
  size_t fitSz = avail / tileB;
  int tilesFit = (int)((fitSz < (size_t)MAXTILES) ? fitSz : (size_t)MAXTILES);
  if (tilesFit < 1) tilesFit = 1;
  int nchunks = (MAXTILES + tilesFit - 1) / tilesFit;
  int tpc = (MAXTILES + nchunks - 1) / nchunks;

  hipMemsetAsync(counts, 0, NEXP * 4, stream);
  hipMemsetAsync(rowTok, 0xFF, (size_t)MAXR * 4, stream);

  convx_k<<<N_TOKENS * HIDDEN / 4 / 256, 256, 0, stream>>>(x, xb);
  transconv_k<<<dim3(FFN / 64, HIDDEN / 64, NEXP), dim3(256, 1, 1), 0, stream>>>(w1, w1bT, HIDDEN, FFN);
  transconv_k<<<dim3(HIDDEN / 64, FFN / 64, NEXP), dim3(256, 1, 1), 0, stream>>>(w2, w2bT, FFN, HIDDEN);
  logits_k<<<N_TOKENS / 32, 256, 0, stream>>>(x, wrt, logitsE);
  route_k<<<N_TOKENS / 256, 256, 0, stream>>>(logitsE, expIdx, expW, counts);
  offsets_k<<<1, 64, 0, stream>>>(counts, padOff, cursor);
  scatter_k<<<N_TOKENS / 256, 256, 0, stream>>>(expIdx, expW, padOff, cursor, rowTok, rowW, tokRow);

  for (int c = 0; c < nchunks; ++c) {
    int ts = c * tpc;
    int rs = ts * BM;
    gemm1_k<<<tpc * (FFN / 128), 256, 0, stream>>>(xb, w1bT, h, rowTok, padOff, ts, rs);
    gemm2_k<<<tpc * (HIDDEN / 128), 256, 0, stream>>>(h, w2bT, y, padOff, ts, rs);
  }
  combine_k<<<N_TOKENS, 256, 0, stream>>>(y, tokRow, rowW, out);
}